// Round 19
// baseline (511.428 us; speedup 1.0000x reference)
//
#include <hip/hip_runtime.h>
#include <hip/hip_fp16.h>

#define B_ 16
#define T_ 256
#define D_ 128
#define H_ 256

typedef _Float16 f16;
typedef __attribute__((ext_vector_type(2))) _Float16 f16x2;
typedef __attribute__((ext_vector_type(4))) int i32x4;

__device__ __forceinline__ float fast_rcp(float x) {
#if __has_builtin(__builtin_amdgcn_rcpf)
    return __builtin_amdgcn_rcpf(x);
#else
    return 1.0f / x;
#endif
}
__device__ __forceinline__ float sigmoid_f(float x) {
    return fast_rcp(1.0f + __expf(-x));
}
__device__ __forceinline__ float tanh_f(float x) {
    float e = __expf(2.0f * x);
    return 1.0f - 2.0f * fast_rcp(1.0f + e);
}
// Padé tanh for the SCORES kernel only (max err ~0.007 vs 2e7 threshold);
// clamp via single v_med3.
__device__ __forceinline__ float tanh_pade(float x) {
#if __has_builtin(__builtin_amdgcn_fmed3f)
    x = __builtin_amdgcn_fmed3f(x, -4.f, 4.f);
#else
    x = fminf(4.f, fmaxf(-4.f, x));
#endif
    float x2 = x * x;
    return x * (27.f + x2) * fast_rcp(27.f + 9.f * x2);
}
__device__ __forceinline__ int dot8(int a, int b, int c) {
#if __has_builtin(__builtin_amdgcn_sdot8)
    return __builtin_amdgcn_sdot8(a, b, c, false);
#else
    int d;
    asm("v_dot8_i32_i4 %0, %1, %2, %3" : "=v"(d) : "v"(a), "v"(b), "v"(c));
    return d;
#endif
}
// VALU-speed cross-lane within a quad (DPP quad_perm, compile-time ctrl)
template <int CTRL>
__device__ __forceinline__ int dpp_quad(int x) {
    return __builtin_amdgcn_update_dpp(0, x, CTRL, 0xF, 0xF, true);
}
#define DPP_XOR1 0xB1  // quad_perm [1,0,3,2]
#define DPP_XOR2 0x4E  // quad_perm [2,3,0,1]

// ---- fused prep + proj3, one 912-block dispatch ----
// blocks 0..383: Whh -> i4 + scales; 384..399: pos mask; 400..911: proj3
// (256 enc + 256 dec, 16 rows/block).
__global__ __launch_bounds__(256)
void k_prep_proj(const float* __restrict__ wa, const float* __restrict__ wb,
                 int* __restrict__ w4a, int* __restrict__ w4b,
                 float* __restrict__ sca, float* __restrict__ scb,
                 const int* __restrict__ tgt, int* __restrict__ pos,
                 const float* __restrict__ inputs,
                 const float* __restrict__ Wenc, const float* __restrict__ benc,
                 const float* __restrict__ We, const float* __restrict__ bihe,
                 const float* __restrict__ bhhe,
                 const float* __restrict__ Wd, const float* __restrict__ bihd,
                 const float* __restrict__ bhhd,
                 f16x2* __restrict__ giAe, f16* __restrict__ giBe,
                 f16x2* __restrict__ giAd, f16* __restrict__ giBd) {
    int blk = blockIdx.x;
    int a = threadIdx.x;
    if (blk < 384) { // ---- weight prep ----
        int wid = blk * 4 + (a >> 6); // [0,1536)
        int l = a & 63;
        const float* W = wid < 768 ? wa : wb;
        int* w4 = wid < 768 ? w4a : w4b;
        float* sc = wid < 768 ? sca : scb;
        int r = wid & 767;
        int g = r >> 8, j = r & 255;
        const float* Wr = W + r * 256;
        float v[8];
        float m = 0.f;
        if (l < 32) {
#pragma unroll
            for (int q = 0; q < 8; ++q) {
                v[q] = Wr[8 * l + q];
                m = fmaxf(m, fabsf(v[q]));
            }
        }
#pragma unroll
        for (int d = 1; d < 64; d <<= 1) m = fmaxf(m, __shfl_xor(m, d));
        float qs = m > 0.f ? 7.f / m : 0.f;
        if (l == 0) sc[r] = m / 49.f;
        if (l < 32) {
            int pk = 0;
#pragma unroll
            for (int q = 0; q < 8; ++q) pk |= ((int)rintf(v[q] * qs) & 15) << (4 * q);
            int hf = l >> 4, i = l & 15;
            w4[(j * 2 + hf) * 48 + g * 16 + i] = pk;
        }
        return;
    }
    if (blk < 400) { // ---- pos mask ----
        __shared__ int pl[256];
        int b = blk - 384;
        pl[a] = T_;
        __syncthreads();
        atomicMin(&pl[tgt[b * 256 + a] & 255], a);
        __syncthreads();
        pos[b * 256 + a] = pl[a];
        return;
    }
    // ---- proj3 ----
    __shared__ float s_in[16][128];
    __shared__ float s_enc[16][256];
    int pblk = blk - 400;
    bool isdec = pblk >= 256;
    int bt0 = (pblk & 255) * 16;
    int b = bt0 >> 8;
    const float* W = isdec ? Wd : We;
    const float* bih = isdec ? bihd : bihe;
    const float* bhh = isdec ? bhhd : bhhe;
    f16x2* giA = isdec ? giAd : giAe;
    f16* giB = isdec ? giBd : giBe;

    int tsrc[16];
#pragma unroll
    for (int tt = 0; tt < 16; ++tt) {
        int t = (bt0 & 255) + tt;
        tsrc[tt] = isdec ? (tgt[(b << 8) + ((t + 255) & 255)] & 255) : t; // roll(targets,1)
    }
#pragma unroll
    for (int it = 0; it < 2; ++it) {
        int idx = a + it * 256;
        int row = idx >> 5, k4 = idx & 31;
        ((float4*)s_in[row])[k4] =
            *(const float4*)(inputs + (b * 256 + tsrc[row]) * 128 + k4 * 4);
    }
    __syncthreads();
    {
        float eacc[16];
#pragma unroll
        for (int tt = 0; tt < 16; ++tt) eacc[tt] = benc[a];
        const float* wr = Wenc + a * 128;
        for (int k = 0; k < 128; k += 4) {
            float4 w4 = *(const float4*)(wr + k);
#pragma unroll
            for (int tt = 0; tt < 16; ++tt) {
                float4 x4 = *(const float4*)&s_in[tt][k];
                eacc[tt] += w4.x * x4.x + w4.y * x4.y + w4.z * x4.z + w4.w * x4.w;
            }
        }
#pragma unroll
        for (int tt = 0; tt < 16; ++tt) s_enc[tt][a] = eacc[tt];
    }
    __syncthreads();
    float acc0[16], acc1[16], acc2[16];
    float b0 = bih[a] + bhh[a];
    float b1 = bih[a + 256] + bhh[a + 256];
    float b2 = bih[a + 512];
#pragma unroll
    for (int tt = 0; tt < 16; ++tt) { acc0[tt] = b0; acc1[tt] = b1; acc2[tt] = b2; }
    const float* w0 = W + a * H_;
    const float* w1 = W + (a + 256) * H_;
    const float* w2 = W + (a + 512) * H_;
    for (int k = 0; k < H_; k += 4) {
        float4 a4 = *(const float4*)(w0 + k);
        float4 b4 = *(const float4*)(w1 + k);
        float4 c4 = *(const float4*)(w2 + k);
#pragma unroll
        for (int tt = 0; tt < 16; ++tt) {
            float4 x4 = *(const float4*)&s_enc[tt][k];
            acc0[tt] += a4.x * x4.x + a4.y * x4.y + a4.z * x4.z + a4.w * x4.w;
            acc1[tt] += b4.x * x4.x + b4.y * x4.y + b4.z * x4.z + b4.w * x4.w;
            acc2[tt] += c4.x * x4.x + c4.y * x4.y + c4.z * x4.z + c4.w * x4.w;
        }
    }
#pragma unroll
    for (int tt = 0; tt < 16; ++tt) {
        int row = bt0 + tt;
        giA[row * 256 + a] = (f16x2){(f16)acc0[tt], (f16)acc1[tt]};
        giB[row * 256 + a] = (f16)acc2[tt];
    }
}

// ---- fused GRU (enc then dec), 16 blocks x 512 threads: one CU per batch ----
// R15-exact (247us proven): i4 weights (48 dwords = fits the 88-reg grant),
// DPP-only cross-lane, one barrier/step, 128B i4 h ping-pong, 1-step gi
// prefetch (R18 falsified the 2-step variant: +9us).
__global__ __launch_bounds__(512)
__attribute__((amdgpu_waves_per_eu(2, 2)))
void k_gru2(const int* __restrict__ w4e, const int* __restrict__ w4d,
            const float* __restrict__ sce, const float* __restrict__ scd,
            const f16x2* __restrict__ giAe, const f16* __restrict__ giBe,
            const f16x2* __restrict__ giAd, const f16* __restrict__ giBd,
            const float* __restrict__ bhhe, const float* __restrict__ bhhd,
            float* __restrict__ enc_out, float* __restrict__ dec_out) {
    __shared__ __align__(16) int sh_h4[2][32];  // buffer: 128B, nibble k = h[k]*7 (i4)
    const int tid = threadIdx.x;
    const int m = blockIdx.x;
    const int j = tid >> 1;
    const int hf = tid & 1;

    if (tid < 64) ((int*)sh_h4)[tid] = 0;
    float hj = 0.f;
    __syncthreads();

    for (int ph = 0; ph < 2; ++ph) {
        const int* w4 = ph ? w4d : w4e;
        const float* scp = ph ? scd : sce;
        const float sc0 = scp[j], sc1 = scp[256 + j], sc2 = scp[512 + j];
        const float bn = (ph ? bhhd : bhhe)[512 + j];
        const f16x2* gA = (ph ? giAd : giAe) + m * (T_ * 256);
        const f16* gB = (ph ? giBd : giBe) + m * (T_ * 256);
        float* outp = (ph ? dec_out : enc_out) + m * (T_ * H_);

        // 48 weight dwords -> arch VGPRs (volatile asm: un-sinkable)
        i32x4 wq[3][4];
        {
            unsigned long long base = (unsigned long long)(w4 + tid * 48);
#pragma unroll
            for (int g = 0; g < 3; ++g)
#pragma unroll
                for (int q4 = 0; q4 < 4; ++q4)
                    asm volatile("global_load_dwordx4 %0, %1, off offset:%2"
                                 : "=v"(wq[g][q4]) : "v"(base), "i"(g * 64 + q4 * 16));
            asm volatile("s_waitcnt vmcnt(0)" ::: "memory");
        }

        f16x2 gab = gA[j];
        f16 gn = gB[j];

        for (int t = 0; t < T_; ++t) {
            const int cur = t & 1;
            int a0 = 0, a1 = 0, a2 = 0;
            const i32x4* hb = (const i32x4*)((const char*)sh_h4 + cur * 128 + hf * 64);
#pragma unroll
            for (int q4 = 0; q4 < 4; ++q4) {
                i32x4 h4 = hb[q4];
#pragma unroll
                for (int d = 0; d < 4; ++d) {
                    a0 = dot8(wq[0][q4][d], h4[d], a0);
                    a1 = dot8(wq[1][q4][d], h4[d], a1);
                    a2 = dot8(wq[2][q4][d], h4[d], a2);
                }
            }
            // prefetch next step's gi (in flight across gates + barrier)
            const int tn = (t < T_ - 1) ? t + 1 : t;
            f16x2 ngab = gA[tn * 256 + j];
            f16 ngn = gB[tn * 256 + j];

            // K-half combine: DPP quad_perm lane^1 (VALU-speed)
            a0 += dpp_quad<DPP_XOR1>(a0);
            a1 += dpp_quad<DPP_XOR1>(a1);
            a2 += dpp_quad<DPP_XOR1>(a2);
            float p0 = (float)a0 * sc0;
            float p1 = (float)a1 * sc1;
            float p2 = (float)a2 * sc2;

            float rr = sigmoid_f((float)gab[0] + p0);
            float zz = sigmoid_f((float)gab[1] + p1);
            float nv = tanh_f((float)gn + rr * (p2 + bn));
            float hn = (1.f - zz) * nv + zz * hj;
            hj = hn;

            if (hf) outp[t * H_ + j] = hn;
            // i4 pack via DPP 0x4E + lane-4u byte write (merge-free)
            int nib = (int)rintf(hn * 7.f) & 15;
            int hi = dpp_quad<DPP_XOR2>(nib);
            if ((tid & 3) == 0)
                ((char*)sh_h4)[(cur ^ 1) * 128 + (tid >> 2)] = (char)(nib | (hi << 4));

            gab = ngab; gn = ngn;
            // LDS-only barrier: gi loads + out stores stay in flight
            asm volatile("s_waitcnt lgkmcnt(0)" ::: "memory");
            __builtin_amdgcn_s_barrier();
        }
    }
}

// ---- kT[b][a][s] = (enc_out@Wk^T)^T, 512 blocks (q moved into k_scores) ----
__global__ __launch_bounds__(256) void k_kT(const float* __restrict__ enc_out,
                                            const float* __restrict__ Wk,
                                            float* __restrict__ kT) {
    __shared__ float tile[8][256];
    int bt0 = blockIdx.x * 8;
    int a = threadIdx.x;
    float acc[8];
#pragma unroll
    for (int tt = 0; tt < 8; ++tt) acc[tt] = 0.f;
    const float* w0 = Wk + a * H_;
    for (int k = 0; k < H_; k += 4) {
        float4 w4 = *(const float4*)(w0 + k);
#pragma unroll
        for (int tt = 0; tt < 8; ++tt) {
            float4 x4 = *(const float4*)(enc_out + (bt0 + tt) * H_ + k);
            acc[tt] += w4.x * x4.x + w4.y * x4.y + w4.z * x4.z + w4.w * x4.w;
        }
    }
#pragma unroll
    for (int tt = 0; tt < 8; ++tt) tile[tt][a] = acc[tt];
    __syncthreads();
    int b = bt0 >> 8, s0 = bt0 & 255;
    float4 f0 = {tile[0][a], tile[1][a], tile[2][a], tile[3][a]};
    float4 f1 = {tile[4][a], tile[5][a], tile[6][a], tile[7][a]};
    *(float4*)(kT + b * (T_ * H_) + a * T_ + s0) = f0;
    *(float4*)(kT + b * (T_ * H_) + a * T_ + s0 + 4) = f1;
}

// ---- scores with fused q-projection ----
// block (b, t0): compute q rows t0..t0+3 from dec_out@Wq (each q row used by
// exactly this block -> zero redundancy), then the masked tanh-score loop.
__global__ __launch_bounds__(256) void k_scores(const float* __restrict__ dec_out,
                                                const float* __restrict__ Wq,
                                                const float* __restrict__ kT,
                                                const float* __restrict__ v,
                                                const int* __restrict__ pos,
                                                float* __restrict__ out) {
    __shared__ float sdec[4][256];
    __shared__ float sq[4][256];
    __shared__ float sv[256];
    int blk = blockIdx.x;
    int b = blk >> 6;
    int t0 = (blk & 63) * 4;
    int s = threadIdx.x;  // doubles as column index 'a' in the q phase
    sv[s] = v[s];
#pragma unroll
    for (int tt = 0; tt < 4; ++tt)
        sdec[tt][s] = dec_out[((b << 8) + t0 + tt) * H_ + s];
    __syncthreads();
    {
        float qa[4] = {0.f, 0.f, 0.f, 0.f};
        const float* wq = Wq + s * H_;
        for (int k = 0; k < H_; k += 4) {
            float4 w4 = *(const float4*)(wq + k);
#pragma unroll
            for (int tt = 0; tt < 4; ++tt) {
                float4 x4 = *(const float4*)&sdec[tt][k];
                qa[tt] += w4.x * x4.x + w4.y * x4.y + w4.z * x4.z + w4.w * x4.w;
            }
        }
#pragma unroll
        for (int tt = 0; tt < 4; ++tt) sq[tt][s] = qa[tt];
    }
    __syncthreads();
    int ps = pos[(b << 8) + s];
    float acc[4] = {0.f, 0.f, 0.f, 0.f};
    const float* kTb = kT + b * (T_ * H_);
    for (int a = 0; a < H_; ++a) {
        float kv = kTb[a * T_ + s];
        float va = sv[a];
#pragma unroll
        for (int tt = 0; tt < 4; ++tt) {
            float th = tanh_pade(sq[tt][a] + kv);
            acc[tt] += va * th;
        }
    }
#pragma unroll
    for (int tt = 0; tt < 4; ++tt) {
        int t = t0 + tt;
        out[((b << 8) + t) * T_ + s] = (t <= ps) ? acc[tt] : -1.0e9f;
    }
}

extern "C" void kernel_launch(void* const* d_in, const int* in_sizes, int n_in,
                              void* d_out, int out_size, void* d_ws, size_t ws_size,
                              hipStream_t stream) {
    (void)in_sizes; (void)n_in; (void)out_size; (void)ws_size;
    const float* inputs   = (const float*)d_in[0];
    const int* targets    = (const int*)d_in[1];
    const float* W_enc   = (const float*)d_in[2];
    const float* b_enc   = (const float*)d_in[3];
    const float* enc_Wih = (const float*)d_in[4];
    const float* enc_Whh = (const float*)d_in[5];
    const float* enc_bih = (const float*)d_in[6];
    const float* enc_bhh = (const float*)d_in[7];
    const float* dec_Wih = (const float*)d_in[8];
    const float* dec_Whh = (const float*)d_in[9];
    const float* dec_bih = (const float*)d_in[10];
    const float* dec_bhh = (const float*)d_in[11];
    const float* Wq = (const float*)d_in[12];
    const float* Wk = (const float*)d_in[13];
    const float* v  = (const float*)d_in[14];
    float* out = (float*)d_out;

    float* ws = (float*)d_ws;
    f16x2* giAe    = (f16x2*)ws;                 // 1,048,576 f
    f16*   giBe    = (f16*)(ws + 1048576);       // 524,288 f
    f16x2* giAd    = (f16x2*)(ws + 1572864);     // 1,048,576 f
    f16*   giBd    = (f16*)(ws + 2621440);       // 524,288 f
    float* enc_out = ws + 3145728;               // 1,048,576 f
    float* dec_out = ws + 4194304;               // 1,048,576 f
    int*   w4e     = (int*)(ws + 5242880);       // 24,576 dw
    int*   w4d     = (int*)(ws + 5292032);       // 24,576 dw
    float* sce     = ws + 5341184;               // 768
    float* scd     = ws + 5341952;               // 768
    int*   pos     = (int*)(ws + 5342720);       // 4,096
    float* kT = (float*)giAd;    // alias: gi dead after gru2

    k_prep_proj<<<912, 256, 0, stream>>>(enc_Whh, dec_Whh, w4e, w4d, sce, scd,
                                         targets, pos, inputs, W_enc, b_enc,
                                         enc_Wih, enc_bih, enc_bhh,
                                         dec_Wih, dec_bih, dec_bhh,
                                         giAe, giBe, giAd, giBd);
    k_gru2<<<16, 512, 0, stream>>>(w4e, w4d, sce, scd, giAe, giBe, giAd, giBd,
                                   enc_bhh, dec_bhh, enc_out, dec_out);
    k_kT<<<512, 256, 0, stream>>>(enc_out, Wk, kT);
    k_scores<<<1024, 256, 0, stream>>>(dec_out, Wq, kT, v, pos, out);
}

// Round 20
// 477.150 us; speedup vs baseline: 1.0718x; 1.0718x over previous
//
#include <hip/hip_runtime.h>
#include <hip/hip_fp16.h>

#define B_ 16
#define T_ 256
#define D_ 128
#define H_ 256

typedef _Float16 f16;
typedef __attribute__((ext_vector_type(2))) _Float16 f16x2;
typedef __attribute__((ext_vector_type(4))) int i32x4;

__device__ __forceinline__ float fast_rcp(float x) {
#if __has_builtin(__builtin_amdgcn_rcpf)
    return __builtin_amdgcn_rcpf(x);
#else
    return 1.0f / x;
#endif
}
__device__ __forceinline__ float sigmoid_f(float x) {
    return fast_rcp(1.0f + __expf(-x));
}
__device__ __forceinline__ float tanh_f(float x) {
    float e = __expf(2.0f * x);
    return 1.0f - 2.0f * fast_rcp(1.0f + e);
}
// Padé tanh for the SCORES kernel only (max err ~0.007 vs 2e7 threshold)
__device__ __forceinline__ float tanh_pade(float x) {
#if __has_builtin(__builtin_amdgcn_fmed3f)
    x = __builtin_amdgcn_fmed3f(x, -4.f, 4.f);
#else
    x = fminf(4.f, fmaxf(-4.f, x));
#endif
    float x2 = x * x;
    return x * (27.f + x2) * fast_rcp(27.f + 9.f * x2);
}
__device__ __forceinline__ int dot8(int a, int b, int c) {
#if __has_builtin(__builtin_amdgcn_sdot8)
    return __builtin_amdgcn_sdot8(a, b, c, false);
#else
    int d;
    asm("v_dot8_i32_i4 %0, %1, %2, %3" : "=v"(d) : "v"(a), "v"(b), "v"(c));
    return d;
#endif
}
// VALU-speed cross-lane within a quad (DPP quad_perm, compile-time ctrl)
template <int CTRL>
__device__ __forceinline__ int dpp_quad(int x) {
    return __builtin_amdgcn_update_dpp(0, x, CTRL, 0xF, 0xF, true);
}
#define DPP_XOR1 0xB1  // quad_perm [1,0,3,2]
#define DPP_XOR2 0x4E  // quad_perm [2,3,0,1]

// ---- fused: weight prep (blocks 0..383) + pos mask (blocks 384..399) ----
__global__ __launch_bounds__(256) void k_prep(const float* __restrict__ wa,
                                              const float* __restrict__ wb,
                                              int* __restrict__ w4a, int* __restrict__ w4b,
                                              float* __restrict__ sca, float* __restrict__ scb,
                                              const int* __restrict__ tgt,
                                              int* __restrict__ pos) {
    int blk = blockIdx.x;
    if (blk >= 384) { // pos part
        __shared__ int pl[256];
        int b = blk - 384, tid = threadIdx.x;
        pl[tid] = T_;
        __syncthreads();
        atomicMin(&pl[tgt[b * 256 + tid] & 255], tid);
        __syncthreads();
        pos[b * 256 + tid] = pl[tid];
        return;
    }
    int wid = blk * 4 + (threadIdx.x >> 6); // [0,1536)
    int l = threadIdx.x & 63;
    const float* W = wid < 768 ? wa : wb;
    int* w4 = wid < 768 ? w4a : w4b;
    float* sc = wid < 768 ? sca : scb;
    int r = wid & 767;
    int g = r >> 8, j = r & 255;
    const float* Wr = W + r * 256;
    float v[8];
    float m = 0.f;
    if (l < 32) {
#pragma unroll
        for (int q = 0; q < 8; ++q) {
            v[q] = Wr[8 * l + q];
            m = fmaxf(m, fabsf(v[q]));
        }
    }
#pragma unroll
    for (int d = 1; d < 64; d <<= 1) m = fmaxf(m, __shfl_xor(m, d));
    float qs = m > 0.f ? 7.f / m : 0.f;
    if (l == 0) sc[r] = m / 49.f;
    if (l < 32) {
        int pk = 0;
#pragma unroll
        for (int q = 0; q < 8; ++q) pk |= ((int)rintf(v[q] * qs) & 15) << (4 * q);
        int hf = l >> 4, i = l & 15;
        w4[(j * 2 + hf) * 48 + g * 16 + i] = pk;
    }
}

// ---- fused encoder-linear + x_proj -> f16 for BOTH GRUs; 16 rows/block ----
__global__ __launch_bounds__(256) void k_proj3(const float* __restrict__ inputs,
                                               const float* __restrict__ Wenc,
                                               const float* __restrict__ benc,
                                               const float* __restrict__ We,
                                               const float* __restrict__ bihe,
                                               const float* __restrict__ bhhe,
                                               const float* __restrict__ Wd,
                                               const float* __restrict__ bihd,
                                               const float* __restrict__ bhhd,
                                               const int* __restrict__ tgt,
                                               f16x2* __restrict__ giAe,
                                               f16* __restrict__ giBe,
                                               f16x2* __restrict__ giAd,
                                               f16* __restrict__ giBd) {
    __shared__ float s_in[16][128];
    __shared__ float s_enc[16][256];
    int blk = blockIdx.x;
    bool isdec = blk >= 256;
    int bt0 = (blk & 255) * 16;
    int b = bt0 >> 8;
    int a = threadIdx.x;
    const float* W = isdec ? Wd : We;
    const float* bih = isdec ? bihd : bihe;
    const float* bhh = isdec ? bhhd : bhhe;
    f16x2* giA = isdec ? giAd : giAe;
    f16* giB = isdec ? giBd : giBe;

    int tsrc[16];
#pragma unroll
    for (int tt = 0; tt < 16; ++tt) {
        int t = (bt0 & 255) + tt;
        tsrc[tt] = isdec ? (tgt[(b << 8) + ((t + 255) & 255)] & 255) : t; // roll(targets,1)
    }
#pragma unroll
    for (int it = 0; it < 2; ++it) {
        int idx = a + it * 256;
        int row = idx >> 5, k4 = idx & 31;
        ((float4*)s_in[row])[k4] =
            *(const float4*)(inputs + (b * 256 + tsrc[row]) * 128 + k4 * 4);
    }
    __syncthreads();
    {
        float eacc[16];
#pragma unroll
        for (int tt = 0; tt < 16; ++tt) eacc[tt] = benc[a];
        const float* wr = Wenc + a * 128;
        for (int k = 0; k < 128; k += 4) {
            float4 w4 = *(const float4*)(wr + k);
#pragma unroll
            for (int tt = 0; tt < 16; ++tt) {
                float4 x4 = *(const float4*)&s_in[tt][k];
                eacc[tt] += w4.x * x4.x + w4.y * x4.y + w4.z * x4.z + w4.w * x4.w;
            }
        }
#pragma unroll
        for (int tt = 0; tt < 16; ++tt) s_enc[tt][a] = eacc[tt];
    }
    __syncthreads();
    float acc0[16], acc1[16], acc2[16];
    float b0 = bih[a] + bhh[a];
    float b1 = bih[a + 256] + bhh[a + 256];
    float b2 = bih[a + 512];
#pragma unroll
    for (int tt = 0; tt < 16; ++tt) { acc0[tt] = b0; acc1[tt] = b1; acc2[tt] = b2; }
    const float* w0 = W + a * H_;
    const float* w1 = W + (a + 256) * H_;
    const float* w2 = W + (a + 512) * H_;
    for (int k = 0; k < H_; k += 4) {
        float4 a4 = *(const float4*)(w0 + k);
        float4 b4 = *(const float4*)(w1 + k);
        float4 c4 = *(const float4*)(w2 + k);
#pragma unroll
        for (int tt = 0; tt < 16; ++tt) {
            float4 x4 = *(const float4*)&s_enc[tt][k];
            acc0[tt] += a4.x * x4.x + a4.y * x4.y + a4.z * x4.z + a4.w * x4.w;
            acc1[tt] += b4.x * x4.x + b4.y * x4.y + b4.z * x4.z + b4.w * x4.w;
            acc2[tt] += c4.x * x4.x + c4.y * x4.y + c4.z * x4.z + c4.w * x4.w;
        }
    }
#pragma unroll
    for (int tt = 0; tt < 16; ++tt) {
        int row = bt0 + tt;
        giA[row * 256 + a] = (f16x2){(f16)acc0[tt], (f16)acc1[tt]};
        giB[row * 256 + a] = (f16)acc2[tt];
    }
}

// ---- fused GRU (enc then dec), 16 blocks x 512 threads: one CU per batch ----
// R15-exact (247us proven): i4 weights (48 dwords = fits the 88-reg grant),
// DPP-only cross-lane, one barrier/step, 128B i4 h ping-pong, 1-step gi prefetch.
__global__ __launch_bounds__(512)
__attribute__((amdgpu_waves_per_eu(2, 2)))
void k_gru2(const int* __restrict__ w4e, const int* __restrict__ w4d,
            const float* __restrict__ sce, const float* __restrict__ scd,
            const f16x2* __restrict__ giAe, const f16* __restrict__ giBe,
            const f16x2* __restrict__ giAd, const f16* __restrict__ giBd,
            const float* __restrict__ bhhe, const float* __restrict__ bhhd,
            float* __restrict__ enc_out, float* __restrict__ dec_out) {
    __shared__ __align__(16) int sh_h4[2][32];  // buffer: 128B, nibble k = h[k]*7 (i4)
    const int tid = threadIdx.x;
    const int m = blockIdx.x;
    const int j = tid >> 1;
    const int hf = tid & 1;

    if (tid < 64) ((int*)sh_h4)[tid] = 0;
    float hj = 0.f;
    __syncthreads();

    for (int ph = 0; ph < 2; ++ph) {
        const int* w4 = ph ? w4d : w4e;
        const float* scp = ph ? scd : sce;
        const float sc0 = scp[j], sc1 = scp[256 + j], sc2 = scp[512 + j];
        const float bn = (ph ? bhhd : bhhe)[512 + j];
        const f16x2* gA = (ph ? giAd : giAe) + m * (T_ * 256);
        const f16* gB = (ph ? giBd : giBe) + m * (T_ * 256);
        float* outp = (ph ? dec_out : enc_out) + m * (T_ * H_);

        // 48 weight dwords -> arch VGPRs (volatile asm: un-sinkable)
        i32x4 wq[3][4];
        {
            unsigned long long base = (unsigned long long)(w4 + tid * 48);
#pragma unroll
            for (int g = 0; g < 3; ++g)
#pragma unroll
                for (int q4 = 0; q4 < 4; ++q4)
                    asm volatile("global_load_dwordx4 %0, %1, off offset:%2"
                                 : "=v"(wq[g][q4]) : "v"(base), "i"(g * 64 + q4 * 16));
            asm volatile("s_waitcnt vmcnt(0)" ::: "memory");
        }

        f16x2 gab = gA[j];
        f16 gn = gB[j];

        for (int t = 0; t < T_; ++t) {
            const int cur = t & 1;
            int a0 = 0, a1 = 0, a2 = 0;
            const i32x4* hb = (const i32x4*)((const char*)sh_h4 + cur * 128 + hf * 64);
#pragma unroll
            for (int q4 = 0; q4 < 4; ++q4) {
                i32x4 h4 = hb[q4];
#pragma unroll
                for (int d = 0; d < 4; ++d) {
                    a0 = dot8(wq[0][q4][d], h4[d], a0);
                    a1 = dot8(wq[1][q4][d], h4[d], a1);
                    a2 = dot8(wq[2][q4][d], h4[d], a2);
                }
            }
            // prefetch next step's gi (in flight across gates + barrier)
            const int tn = (t < T_ - 1) ? t + 1 : t;
            f16x2 ngab = gA[tn * 256 + j];
            f16 ngn = gB[tn * 256 + j];

            // K-half combine: DPP quad_perm lane^1 (VALU-speed)
            a0 += dpp_quad<DPP_XOR1>(a0);
            a1 += dpp_quad<DPP_XOR1>(a1);
            a2 += dpp_quad<DPP_XOR1>(a2);
            float p0 = (float)a0 * sc0;
            float p1 = (float)a1 * sc1;
            float p2 = (float)a2 * sc2;

            float rr = sigmoid_f((float)gab[0] + p0);
            float zz = sigmoid_f((float)gab[1] + p1);
            float nv = tanh_f((float)gn + rr * (p2 + bn));
            float hn = (1.f - zz) * nv + zz * hj;
            hj = hn;

            if (hf) outp[t * H_ + j] = hn;
            // i4 pack via DPP 0x4E + lane-4u byte write (merge-free)
            int nib = (int)rintf(hn * 7.f) & 15;
            int hi = dpp_quad<DPP_XOR2>(nib);
            if ((tid & 3) == 0)
                ((char*)sh_h4)[(cur ^ 1) * 128 + (tid >> 2)] = (char)(nib | (hi << 4));

            gab = ngab; gn = ngn;
            // LDS-only barrier: gi loads + out stores stay in flight
            asm volatile("s_waitcnt lgkmcnt(0)" ::: "memory");
            __builtin_amdgcn_s_barrier();
        }
    }
}

// ---- q = dec_out@Wq^T ; kT = (enc_out@Wk^T)^T -- 16 rows/block, 512 blocks ----
// 16 rows/block halves the Wq/Wk L2 re-read stream vs 8 rows (the R17 proj3
// lever applied here): 256 MB -> 128 MB at unchanged FMA count.
__global__ __launch_bounds__(256) void k_qk(const float* __restrict__ dec_out,
                                            const float* __restrict__ Wq,
                                            const float* __restrict__ enc_out,
                                            const float* __restrict__ Wk,
                                            float* __restrict__ q,
                                            float* __restrict__ kT) {
    __shared__ float tile[16][256];
    int blk = blockIdx.x;
    bool isq = blk < 256;
    int bt0 = (blk & 255) * 16;
    const float* in = isq ? dec_out : enc_out;
    const float* W = isq ? Wq : Wk;
    int a = threadIdx.x;
    float acc[16];
#pragma unroll
    for (int tt = 0; tt < 16; ++tt) acc[tt] = 0.f;
    const float* w0 = W + a * H_;
    for (int k = 0; k < H_; k += 4) {
        float4 w4 = *(const float4*)(w0 + k);
#pragma unroll
        for (int tt = 0; tt < 16; ++tt) {
            float4 x4 = *(const float4*)(in + (bt0 + tt) * H_ + k);
            acc[tt] += w4.x * x4.x + w4.y * x4.y + w4.z * x4.z + w4.w * x4.w;
        }
    }
    if (isq) {
#pragma unroll
        for (int tt = 0; tt < 16; ++tt) q[(bt0 + tt) * H_ + a] = acc[tt];
    } else {
#pragma unroll
        for (int tt = 0; tt < 16; ++tt) tile[tt][a] = acc[tt];
        __syncthreads();
        int b = bt0 >> 8, s0 = bt0 & 255;
#pragma unroll
        for (int i4 = 0; i4 < 4; ++i4) {
            float4 f = {tile[i4 * 4 + 0][a], tile[i4 * 4 + 1][a],
                        tile[i4 * 4 + 2][a], tile[i4 * 4 + 3][a]};
            *(float4*)(kT + b * (T_ * H_) + a * T_ + s0 + i4 * 4) = f;
        }
    }
}

// ---- logits[b,t,s] = mask ? v . tanh(q[b,t,:]+k[b,s,:]) : -1e9 ----
__global__ __launch_bounds__(256) void k_scores(const float* __restrict__ q,
                                                const float* __restrict__ kT,
                                                const float* __restrict__ v,
                                                const int* __restrict__ pos,
                                                float* __restrict__ out) {
    __shared__ float sq[4][256];
    __shared__ float sv[256];
    int blk = blockIdx.x;
    int b = blk >> 6;
    int t0 = (blk & 63) * 4;
    int s = threadIdx.x;
    sv[s] = v[s];
#pragma unroll
    for (int tt = 0; tt < 4; ++tt)
        sq[tt][s] = q[((b << 8) + t0 + tt) * H_ + s];
    __syncthreads();
    int ps = pos[(b << 8) + s];
    float acc[4] = {0.f, 0.f, 0.f, 0.f};
    const float* kTb = kT + b * (T_ * H_);
    for (int a = 0; a < H_; ++a) {
        float kv = kTb[a * T_ + s];
        float va = sv[a];
#pragma unroll
        for (int tt = 0; tt < 4; ++tt) {
            float th = tanh_pade(sq[tt][a] + kv);
            acc[tt] += va * th;
        }
    }
#pragma unroll
    for (int tt = 0; tt < 4; ++tt) {
        int t = t0 + tt;
        out[((b << 8) + t) * T_ + s] = (t <= ps) ? acc[tt] : -1.0e9f;
    }
}

extern "C" void kernel_launch(void* const* d_in, const int* in_sizes, int n_in,
                              void* d_out, int out_size, void* d_ws, size_t ws_size,
                              hipStream_t stream) {
    (void)in_sizes; (void)n_in; (void)out_size; (void)ws_size;
    const float* inputs   = (const float*)d_in[0];
    const int* targets    = (const int*)d_in[1];
    const float* W_enc   = (const float*)d_in[2];
    const float* b_enc   = (const float*)d_in[3];
    const float* enc_Wih = (const float*)d_in[4];
    const float* enc_Whh = (const float*)d_in[5];
    const float* enc_bih = (const float*)d_in[6];
    const float* enc_bhh = (const float*)d_in[7];
    const float* dec_Wih = (const float*)d_in[8];
    const float* dec_Whh = (const float*)d_in[9];
    const float* dec_bih = (const float*)d_in[10];
    const float* dec_bhh = (const float*)d_in[11];
    const float* Wq = (const float*)d_in[12];
    const float* Wk = (const float*)d_in[13];
    const float* v  = (const float*)d_in[14];
    float* out = (float*)d_out;

    float* ws = (float*)d_ws;
    f16x2* giAe    = (f16x2*)ws;                 // 1,048,576 f
    f16*   giBe    = (f16*)(ws + 1048576);       // 524,288 f
    f16x2* giAd    = (f16x2*)(ws + 1572864);     // 1,048,576 f
    f16*   giBd    = (f16*)(ws + 2621440);       // 524,288 f
    float* enc_out = ws + 3145728;               // 1,048,576 f
    float* dec_out = ws + 4194304;               // 1,048,576 f
    int*   w4e     = (int*)(ws + 5242880);       // 24,576 dw
    int*   w4d     = (int*)(ws + 5292032);       // 24,576 dw
    float* sce     = ws + 5341184;               // 768
    float* scd     = ws + 5341952;               // 768
    int*   pos     = (int*)(ws + 5342720);       // 4,096
    float* q  = (float*)giAe;    // alias: gi dead after gru2
    float* kT = (float*)giAd;    // alias

    k_prep<<<400, 256, 0, stream>>>(enc_Whh, dec_Whh, w4e, w4d, sce, scd, targets, pos);
    k_proj3<<<512, 256, 0, stream>>>(inputs, W_enc, b_enc,
                                     enc_Wih, enc_bih, enc_bhh,
                                     dec_Wih, dec_bih, dec_bhh,
                                     targets, giAe, giBe, giAd, giBd);
    k_gru2<<<16, 512, 0, stream>>>(w4e, w4d, sce, scd, giAe, giBe, giAd, giBd,
                                   enc_bhh, dec_bhh, enc_out, dec_out);
    k_qk<<<512, 256, 0, stream>>>(dec_out, Wq, enc_out, Wk, q, kT);
    k_scores<<<1024, 256, 0, stream>>>(q, kT, v, pos, out);
}

// Round 21
// 412.746 us; speedup vs baseline: 1.2391x; 1.1560x over previous
//
#include <hip/hip_runtime.h>
#include <hip/hip_fp16.h>

#define B_ 16
#define T_ 256
#define D_ 128
#define H_ 256

typedef _Float16 f16;
typedef __attribute__((ext_vector_type(2))) _Float16 f16x2;
typedef __attribute__((ext_vector_type(4))) int i32x4;

__device__ __forceinline__ float fast_rcp(float x) {
#if __has_builtin(__builtin_amdgcn_rcpf)
    return __builtin_amdgcn_rcpf(x);
#else
    return 1.0f / x;
#endif
}
__device__ __forceinline__ float sigmoid_f(float x) {
    return fast_rcp(1.0f + __expf(-x));
}
__device__ __forceinline__ float tanh_f(float x) {
    float e = __expf(2.0f * x);
    return 1.0f - 2.0f * fast_rcp(1.0f + e);
}
// Padé tanh for the SCORES kernel only (max err ~0.007 vs 2e7 threshold)
__device__ __forceinline__ float tanh_pade(float x) {
#if __has_builtin(__builtin_amdgcn_fmed3f)
    x = __builtin_amdgcn_fmed3f(x, -4.f, 4.f);
#else
    x = fminf(4.f, fmaxf(-4.f, x));
#endif
    float x2 = x * x;
    return x * (27.f + x2) * fast_rcp(27.f + 9.f * x2);
}
__device__ __forceinline__ int dot8(int a, int b, int c) {
#if __has_builtin(__builtin_amdgcn_sdot8)
    return __builtin_amdgcn_sdot8(a, b, c, false);
#else
    int d;
    asm("v_dot8_i32_i4 %0, %1, %2, %3" : "=v"(d) : "v"(a), "v"(b), "v"(c));
    return d;
#endif
}
// VALU-speed cross-lane within a quad (DPP quad_perm, compile-time ctrl)
template <int CTRL>
__device__ __forceinline__ int dpp_quad(int x) {
    return __builtin_amdgcn_update_dpp(0, x, CTRL, 0xF, 0xF, true);
}
#define DPP_XOR1 0xB1  // quad_perm [1,0,3,2]
#define DPP_XOR2 0x4E  // quad_perm [2,3,0,1]

// ---- one GRU phase (256 steps) for batch m, 512 threads ----
// R15-proven body: i4 weights (48 dwords, fits 88-reg grant), DPP-only
// cross-lane, one barrier/step, 128B i4 h ping-pong, 1-step gi prefetch.
// Caller must have initialized sh_h4 buffer 0 + hj and synced.
__device__ __forceinline__ void gru_phase(const int* __restrict__ w4,
                                          const float* __restrict__ scp,
                                          const float* __restrict__ bhp,
                                          const f16x2* __restrict__ gA,
                                          const f16* __restrict__ gB,
                                          float* __restrict__ outp,
                                          float& hj, int* sh_h4, int tid) {
    const int j = tid >> 1;
    const int hf = tid & 1;
    const float sc0 = scp[j], sc1 = scp[256 + j], sc2 = scp[512 + j];
    const float bn = bhp[512 + j];

    i32x4 wq[3][4];
    {
        unsigned long long base = (unsigned long long)(w4 + tid * 48);
#pragma unroll
        for (int g = 0; g < 3; ++g)
#pragma unroll
            for (int q4 = 0; q4 < 4; ++q4)
                asm volatile("global_load_dwordx4 %0, %1, off offset:%2"
                             : "=v"(wq[g][q4]) : "v"(base), "i"(g * 64 + q4 * 16));
        asm volatile("s_waitcnt vmcnt(0)" ::: "memory");
    }

    f16x2 gab = gA[j];
    f16 gn = gB[j];

    for (int t = 0; t < T_; ++t) {
        const int cur = t & 1;
        int a0 = 0, a1 = 0, a2 = 0;
        const i32x4* hb = (const i32x4*)((const char*)sh_h4 + cur * 128 + hf * 64);
#pragma unroll
        for (int q4 = 0; q4 < 4; ++q4) {
            i32x4 h4 = hb[q4];
#pragma unroll
            for (int d = 0; d < 4; ++d) {
                a0 = dot8(wq[0][q4][d], h4[d], a0);
                a1 = dot8(wq[1][q4][d], h4[d], a1);
                a2 = dot8(wq[2][q4][d], h4[d], a2);
            }
        }
        const int tn = (t < T_ - 1) ? t + 1 : t;
        f16x2 ngab = gA[tn * 256 + j];
        f16 ngn = gB[tn * 256 + j];

        a0 += dpp_quad<DPP_XOR1>(a0);
        a1 += dpp_quad<DPP_XOR1>(a1);
        a2 += dpp_quad<DPP_XOR1>(a2);
        float p0 = (float)a0 * sc0;
        float p1 = (float)a1 * sc1;
        float p2 = (float)a2 * sc2;

        float rr = sigmoid_f((float)gab[0] + p0);
        float zz = sigmoid_f((float)gab[1] + p1);
        float nv = tanh_f((float)gn + rr * (p2 + bn));
        float hn = (1.f - zz) * nv + zz * hj;
        hj = hn;

        if (hf) outp[t * H_ + j] = hn;
        int nib = (int)rintf(hn * 7.f) & 15;
        int hi = dpp_quad<DPP_XOR2>(nib);
        if ((tid & 3) == 0)
            ((char*)sh_h4)[(cur ^ 1) * 128 + (tid >> 2)] = (char)(nib | (hi << 4));

        gab = ngab; gn = ngn;
        asm volatile("s_waitcnt lgkmcnt(0)" ::: "memory");
        __builtin_amdgcn_s_barrier();
    }
}

// ---- D1: weight prep (0..383) + pos (384..399) + proj3-ENC (400..655) ----
__global__ __launch_bounds__(256)
void k_prep_pe(const float* __restrict__ wa, const float* __restrict__ wb,
               int* __restrict__ w4a, int* __restrict__ w4b,
               float* __restrict__ sca, float* __restrict__ scb,
               const int* __restrict__ tgt, int* __restrict__ pos,
               const float* __restrict__ inputs,
               const float* __restrict__ Wenc, const float* __restrict__ benc,
               const float* __restrict__ We, const float* __restrict__ bihe,
               const float* __restrict__ bhhe,
               f16x2* __restrict__ giAe, f16* __restrict__ giBe) {
    int blk = blockIdx.x;
    int a = threadIdx.x;
    if (blk < 384) { // weight prep
        int wid = blk * 4 + (a >> 6);
        int l = a & 63;
        const float* W = wid < 768 ? wa : wb;
        int* w4 = wid < 768 ? w4a : w4b;
        float* sc = wid < 768 ? sca : scb;
        int r = wid & 767;
        int g = r >> 8, j = r & 255;
        const float* Wr = W + r * 256;
        float v[8];
        float m = 0.f;
        if (l < 32) {
#pragma unroll
            for (int q = 0; q < 8; ++q) {
                v[q] = Wr[8 * l + q];
                m = fmaxf(m, fabsf(v[q]));
            }
        }
#pragma unroll
        for (int d = 1; d < 64; d <<= 1) m = fmaxf(m, __shfl_xor(m, d));
        float qs = m > 0.f ? 7.f / m : 0.f;
        if (l == 0) sc[r] = m / 49.f;
        if (l < 32) {
            int pk = 0;
#pragma unroll
            for (int q = 0; q < 8; ++q) pk |= ((int)rintf(v[q] * qs) & 15) << (4 * q);
            int hf = l >> 4, i = l & 15;
            w4[(j * 2 + hf) * 48 + g * 16 + i] = pk;
        }
        return;
    }
    if (blk < 400) { // pos
        __shared__ int pl[256];
        int b = blk - 384;
        pl[a] = T_;
        __syncthreads();
        atomicMin(&pl[tgt[b * 256 + a] & 255], a);
        __syncthreads();
        pos[b * 256 + a] = pl[a];
        return;
    }
    // proj3-enc, 16 rows/block
    __shared__ float s_in[16][128];
    __shared__ float s_enc[16][256];
    int pblk = blk - 400;
    int bt0 = pblk * 16;
    int b = bt0 >> 8;
    {
        int idx = a * 4 >> 7, k = (a * 4) & 127; // row, k
        *(float4*)&s_in[idx][k] = *(const float4*)(inputs + (b * 256 + (bt0 & 255) + idx) * 128 + k);
    }
    {
        int idx = a + 256;
        int row = idx >> 5, k4 = idx & 31;
        ((float4*)s_in[row])[k4] =
            *(const float4*)(inputs + (b * 256 + (bt0 & 255) + row) * 128 + k4 * 4);
    }
    // fix: first staging covers slots 0..255 (rows 0..7); redo uniformly:
    __syncthreads();
#pragma unroll
    for (int it = 0; it < 2; ++it) {
        int idx = a + it * 256;
        int row = idx >> 5, k4 = idx & 31;
        ((float4*)s_in[row])[k4] =
            *(const float4*)(inputs + (b * 256 + (bt0 & 255) + row) * 128 + k4 * 4);
    }
    __syncthreads();
    {
        float eacc[16];
#pragma unroll
        for (int tt = 0; tt < 16; ++tt) eacc[tt] = benc[a];
        const float* wr = Wenc + a * 128;
        for (int k = 0; k < 128; k += 4) {
            float4 w4 = *(const float4*)(wr + k);
#pragma unroll
            for (int tt = 0; tt < 16; ++tt) {
                float4 x4 = *(const float4*)&s_in[tt][k];
                eacc[tt] += w4.x * x4.x + w4.y * x4.y + w4.z * x4.z + w4.w * x4.w;
            }
        }
#pragma unroll
        for (int tt = 0; tt < 16; ++tt) s_enc[tt][a] = eacc[tt];
    }
    __syncthreads();
    float acc0[16], acc1[16], acc2[16];
    float b0 = bihe[a] + bhhe[a];
    float b1 = bihe[a + 256] + bhhe[a + 256];
    float b2 = bihe[a + 512];
#pragma unroll
    for (int tt = 0; tt < 16; ++tt) { acc0[tt] = b0; acc1[tt] = b1; acc2[tt] = b2; }
    const float* w0 = We + a * H_;
    const float* w1 = We + (a + 256) * H_;
    const float* w2 = We + (a + 512) * H_;
    for (int k = 0; k < H_; k += 4) {
        float4 a4 = *(const float4*)(w0 + k);
        float4 b4 = *(const float4*)(w1 + k);
        float4 c4 = *(const float4*)(w2 + k);
#pragma unroll
        for (int tt = 0; tt < 16; ++tt) {
            float4 x4 = *(const float4*)&s_enc[tt][k];
            acc0[tt] += a4.x * x4.x + a4.y * x4.y + a4.z * x4.z + a4.w * x4.w;
            acc1[tt] += b4.x * x4.x + b4.y * x4.y + b4.z * x4.z + b4.w * x4.w;
            acc2[tt] += c4.x * x4.x + c4.y * x4.y + c4.z * x4.z + c4.w * x4.w;
        }
    }
#pragma unroll
    for (int tt = 0; tt < 16; ++tt) {
        int row = bt0 + tt;
        giAe[row * 256 + a] = (f16x2){(f16)acc0[tt], (f16)acc1[tt]};
        giBe[row * 256 + a] = (f16)acc2[tt];
    }
}

// ---- D2: blocks 0-15 = enc-GRU; blocks 16-143 = proj3-DEC (32 rows, 512 thr) ----
__global__ __launch_bounds__(512)
__attribute__((amdgpu_waves_per_eu(2, 2)))
void k_egru_pd(const int* __restrict__ w4e, const float* __restrict__ sce,
               const f16x2* __restrict__ giAe, const f16* __restrict__ giBe,
               const float* __restrict__ bhhe,
               float* __restrict__ enc_out, float* __restrict__ hT,
               const float* __restrict__ inputs,
               const float* __restrict__ Wenc, const float* __restrict__ benc,
               const float* __restrict__ Wd, const float* __restrict__ bihd,
               const float* __restrict__ bhhd, const int* __restrict__ tgt,
               f16x2* __restrict__ giAd, f16* __restrict__ giBd) {
    __shared__ __align__(16) int sh_h4[2][32];
    __shared__ float s_in[32][128];
    __shared__ float s_enc[32][256];
    const int blk = blockIdx.x;
    const int tid = threadIdx.x;
    if (blk < 16) { // ---- enc GRU, batch m = blk ----
        const int m = blk;
        if (tid < 64) ((int*)sh_h4)[tid] = 0;
        float hj = 0.f;
        __syncthreads();
        gru_phase(w4e, sce, bhhe, giAe + m * (T_ * 256), giBe + m * (T_ * 256),
                  enc_out + m * (T_ * H_), hj, &sh_h4[0][0], tid);
        if (tid & 1) hT[m * H_ + (tid >> 1)] = hj;
        return;
    }
    // ---- proj3-dec: 32 rows/block ----
    const int pblk = blk - 16;
    const int bt0 = pblk * 32;
    const int b = bt0 >> 8;
    const int a = tid & 255;
    const int half = tid >> 8;
    int tsrc[16];
#pragma unroll
    for (int i = 0; i < 16; ++i) {
        int t = (bt0 & 255) + half * 16 + i;
        tsrc[i] = tgt[(b << 8) + ((t + 255) & 255)] & 255; // roll(targets,1)
    }
    // stage 32 rows (1024 float4 slots, 2/thread); rows from both halves'
    // gather indices -> recompute tsrc for arbitrary rows:
#pragma unroll
    for (int it = 0; it < 2; ++it) {
        int idx = tid + it * 512;
        int row = idx >> 5, k4 = idx & 31;
        int t = (bt0 & 255) + row;
        int rs = tgt[(b << 8) + ((t + 255) & 255)] & 255;
        ((float4*)s_in[row])[k4] = *(const float4*)(inputs + (b * 256 + rs) * 128 + k4 * 4);
    }
    __syncthreads();
    {
        float eacc[16];
#pragma unroll
        for (int i = 0; i < 16; ++i) eacc[i] = benc[a];
        const float* wr = Wenc + a * 128;
        for (int k = 0; k < 128; k += 4) {
            float4 w4 = *(const float4*)(wr + k);
#pragma unroll
            for (int i = 0; i < 16; ++i) {
                float4 x4 = *(const float4*)&s_in[half * 16 + i][k];
                eacc[i] += w4.x * x4.x + w4.y * x4.y + w4.z * x4.z + w4.w * x4.w;
            }
        }
#pragma unroll
        for (int i = 0; i < 16; ++i) s_enc[half * 16 + i][a] = eacc[i];
    }
    __syncthreads();
    float acc0[16], acc1[16], acc2[16];
    float b0 = bihd[a] + bhhd[a];
    float b1 = bihd[a + 256] + bhhd[a + 256];
    float b2 = bihd[a + 512];
#pragma unroll
    for (int i = 0; i < 16; ++i) { acc0[i] = b0; acc1[i] = b1; acc2[i] = b2; }
    const float* w0 = Wd + a * H_;
    const float* w1 = Wd + (a + 256) * H_;
    const float* w2 = Wd + (a + 512) * H_;
    for (int k = 0; k < H_; k += 4) {
        float4 a4 = *(const float4*)(w0 + k);
        float4 b4 = *(const float4*)(w1 + k);
        float4 c4 = *(const float4*)(w2 + k);
#pragma unroll
        for (int i = 0; i < 16; ++i) {
            float4 x4 = *(const float4*)&s_enc[half * 16 + i][k];
            acc0[i] += a4.x * x4.x + a4.y * x4.y + a4.z * x4.z + a4.w * x4.w;
            acc1[i] += b4.x * x4.x + b4.y * x4.y + b4.z * x4.z + b4.w * x4.w;
            acc2[i] += c4.x * x4.x + c4.y * x4.y + c4.z * x4.z + c4.w * x4.w;
        }
    }
#pragma unroll
    for (int i = 0; i < 16; ++i) {
        int row = bt0 + half * 16 + i;
        giAd[row * 256 + a] = (f16x2){(f16)acc0[i], (f16)acc1[i]};
        giBd[row * 256 + a] = (f16)acc2[i];
    }
    (void)tsrc;
}

// ---- D3: blocks 0-15 = dec-GRU; blocks 16-143 = kT (32 rows, 512 thr) ----
__global__ __launch_bounds__(512)
__attribute__((amdgpu_waves_per_eu(2, 2)))
void k_dgru_kt(const int* __restrict__ w4d, const float* __restrict__ scd,
               const f16x2* __restrict__ giAd, const f16* __restrict__ giBd,
               const float* __restrict__ bhhd,
               float* __restrict__ dec_out, const float* __restrict__ hT,
               const float* __restrict__ enc_out, const float* __restrict__ Wk,
               float* __restrict__ kT) {
    __shared__ __align__(16) int sh_h4[2][32];
    __shared__ float tile[32][256];
    const int blk = blockIdx.x;
    const int tid = threadIdx.x;
    if (blk < 16) { // ---- dec GRU, batch m = blk ----
        const int m = blk;
        const int j = tid >> 1;
        float hj = hT[m * H_ + j];
        int nib = (int)rintf(hj * 7.f) & 15;
        int hi = dpp_quad<DPP_XOR2>(nib);
        if ((tid & 3) == 0)
            ((char*)sh_h4)[tid >> 2] = (char)(nib | (hi << 4));
        __syncthreads();
        gru_phase(w4d, scd, bhhd, giAd + m * (T_ * 256), giBd + m * (T_ * 256),
                  dec_out + m * (T_ * H_), hj, &sh_h4[0][0], tid);
        return;
    }
    // ---- kT: 32 rows (consecutive s of one batch) per block ----
    const int kblk = blk - 16;
    const int bt0 = kblk * 32;
    const int b = bt0 >> 8, s0 = bt0 & 255;
    const int a = tid & 255;
    const int half = tid >> 8;
    float acc[16];
#pragma unroll
    for (int i = 0; i < 16; ++i) acc[i] = 0.f;
    const float* w0 = Wk + a * H_;
    for (int k = 0; k < H_; k += 4) {
        float4 w4 = *(const float4*)(w0 + k);
#pragma unroll
        for (int i = 0; i < 16; ++i) {
            float4 x4 = *(const float4*)(enc_out + (bt0 + half * 16 + i) * H_ + k);
            acc[i] += w4.x * x4.x + w4.y * x4.y + w4.z * x4.z + w4.w * x4.w;
        }
    }
#pragma unroll
    for (int i = 0; i < 16; ++i) tile[half * 16 + i][a] = acc[i];
    __syncthreads();
#pragma unroll
    for (int i4 = 0; i4 < 4; ++i4) {
        float4 f = {tile[half * 16 + i4 * 4 + 0][a], tile[half * 16 + i4 * 4 + 1][a],
                    tile[half * 16 + i4 * 4 + 2][a], tile[half * 16 + i4 * 4 + 3][a]};
        *(float4*)(kT + b * (T_ * H_) + a * T_ + s0 + half * 16 + i4 * 4) = f;
    }
}

// ---- D4: q = dec_out@Wq^T, 16 rows/block, 256 blocks ----
__global__ __launch_bounds__(256) void k_q(const float* __restrict__ dec_out,
                                           const float* __restrict__ Wq,
                                           float* __restrict__ q) {
    int bt0 = blockIdx.x * 16;
    int a = threadIdx.x;
    float acc[16];
#pragma unroll
    for (int tt = 0; tt < 16; ++tt) acc[tt] = 0.f;
    const float* w0 = Wq + a * H_;
    for (int k = 0; k < H_; k += 4) {
        float4 w4 = *(const float4*)(w0 + k);
#pragma unroll
        for (int tt = 0; tt < 16; ++tt) {
            float4 x4 = *(const float4*)(dec_out + (bt0 + tt) * H_ + k);
            acc[tt] += w4.x * x4.x + w4.y * x4.y + w4.z * x4.z + w4.w * x4.w;
        }
    }
#pragma unroll
    for (int tt = 0; tt < 16; ++tt) q[(bt0 + tt) * H_ + a] = acc[tt];
}

// ---- D5: logits[b,t,s] = mask ? v . tanh(q+k) : -1e9 ----
__global__ __launch_bounds__(256) void k_scores(const float* __restrict__ q,
                                                const float* __restrict__ kT,
                                                const float* __restrict__ v,
                                                const int* __restrict__ pos,
                                                float* __restrict__ out) {
    __shared__ float sq[4][256];
    __shared__ float sv[256];
    int blk = blockIdx.x;
    int b = blk >> 6;
    int t0 = (blk & 63) * 4;
    int s = threadIdx.x;
    sv[s] = v[s];
#pragma unroll
    for (int tt = 0; tt < 4; ++tt)
        sq[tt][s] = q[((b << 8) + t0 + tt) * H_ + s];
    __syncthreads();
    int ps = pos[(b << 8) + s];
    float acc[4] = {0.f, 0.f, 0.f, 0.f};
    const float* kTb = kT + b * (T_ * H_);
    for (int a = 0; a < H_; ++a) {
        float kv = kTb[a * T_ + s];
        float va = sv[a];
#pragma unroll
        for (int tt = 0; tt < 4; ++tt) {
            float th = tanh_pade(sq[tt][a] + kv);
            acc[tt] += va * th;
        }
    }
#pragma unroll
    for (int tt = 0; tt < 4; ++tt) {
        int t = t0 + tt;
        out[((b << 8) + t) * T_ + s] = (t <= ps) ? acc[tt] : -1.0e9f;
    }
}

extern "C" void kernel_launch(void* const* d_in, const int* in_sizes, int n_in,
                              void* d_out, int out_size, void* d_ws, size_t ws_size,
                              hipStream_t stream) {
    (void)in_sizes; (void)n_in; (void)out_size; (void)ws_size;
    const float* inputs   = (const float*)d_in[0];
    const int* targets    = (const int*)d_in[1];
    const float* W_enc   = (const float*)d_in[2];
    const float* b_enc   = (const float*)d_in[3];
    const float* enc_Wih = (const float*)d_in[4];
    const float* enc_Whh = (const float*)d_in[5];
    const float* enc_bih = (const float*)d_in[6];
    const float* enc_bhh = (const float*)d_in[7];
    const float* dec_Wih = (const float*)d_in[8];
    const float* dec_Whh = (const float*)d_in[9];
    const float* dec_bih = (const float*)d_in[10];
    const float* dec_bhh = (const float*)d_in[11];
    const float* Wq = (const float*)d_in[12];
    const float* Wk = (const float*)d_in[13];
    const float* v  = (const float*)d_in[14];
    float* out = (float*)d_out;

    float* ws = (float*)d_ws;
    f16x2* giAe    = (f16x2*)ws;                 // 1,048,576 f
    f16*   giBe    = (f16*)(ws + 1048576);       // 524,288 f
    f16x2* giAd    = (f16x2*)(ws + 1572864);     // 1,048,576 f
    f16*   giBd    = (f16*)(ws + 2621440);       // 524,288 f
    float* enc_out = ws + 3145728;               // 1,048,576 f
    float* dec_out = ws + 4194304;               // 1,048,576 f
    int*   w4e     = (int*)(ws + 5242880);       // 24,576 dw
    int*   w4d     = (int*)(ws + 5292032);       // 24,576 dw
    float* sce     = ws + 5341184;               // 768
    float* scd     = ws + 5341952;               // 768
    int*   pos     = (int*)(ws + 5342720);       // 4,096
    float* hT      = ws + 5346816;               // 4,096
    float* kT = (float*)giAe;    // alias: giAe dead after D2 (enc-GRU)
    float* q  = (float*)giAd;    // alias: giAd dead after D3 (dec-GRU)

    k_prep_pe<<<656, 256, 0, stream>>>(enc_Whh, dec_Whh, w4e, w4d, sce, scd,
                                       targets, pos, inputs, W_enc, b_enc,
                                       enc_Wih, enc_bih, enc_bhh, giAe, giBe);
    k_egru_pd<<<144, 512, 0, stream>>>(w4e, sce, giAe, giBe, enc_bhh, enc_out, hT,
                                       inputs, W_enc, b_enc,
                                       dec_Wih, dec_bih, dec_bhh, targets,
                                       giAd, giBd);
    k_dgru_kt<<<144, 512, 0, stream>>>(w4d, scd, giAd, giBd, dec_bhh, dec_out, hT,
                                       enc_out, Wk, kT);
    k_q<<<256, 256, 0, stream>>>(dec_out, Wq, q);
    k_scores<<<1024, 256, 0, stream>>>(q, kT, v, pos, out);
}